// Round 2
// baseline (226.491 us; speedup 1.0000x reference)
//
#include <hip/hip_runtime.h>
#include <hip/hip_bf16.h>

#define NQ 12
#define NSTATES (1 << NQ)   // 4096
#define THREADS 256

// One block per batch element. Full statevector in LDS (re/im split arrays,
// 32 KB total). Gates applied sequentially with a barrier between each; all
// pair updates within a gate are disjoint.
__global__ __launch_bounds__(THREADS) void qsim_kernel(
    const float* __restrict__ x,   // [B, NQ] float32
    const float* __restrict__ w,   // [L, NQ] float32
    float* __restrict__ out,       // [B, NQ] float32
    int L)
{
    __shared__ float re[NSTATES];
    __shared__ float im[NSTATES];
    __shared__ float wsum[THREADS / 64][NQ];

    const int b = blockIdx.x;
    const int t = threadIdx.x;

    // init |0...0>
    for (int i = t; i < NSTATES; i += THREADS) { re[i] = 0.0f; im[i] = 0.0f; }
    if (t == 0) re[0] = 1.0f;
    __syncthreads();

    // RX on qubit q with angle theta. Qubit q <-> bit (NQ-1-q) of the index.
    auto apply_rx = [&](int q, float theta) {
        const int bit  = NQ - 1 - q;
        const int mask = 1 << bit;
        const float h  = 0.5f * theta;
        const float c  = cosf(h);
        const float s  = sinf(h);
        #pragma unroll
        for (int it = 0; it < NSTATES / 2 / THREADS; ++it) {
            const int p  = t + it * THREADS;
            const int i0 = ((p >> bit) << (bit + 1)) | (p & (mask - 1));
            const int i1 = i0 | mask;
            const float a0r = re[i0], a0i = im[i0];
            const float a1r = re[i1], a1i = im[i1];
            // [c, -i s; -i s, c] applied to (a0, a1)
            re[i0] = c * a0r + s * a1i;
            im[i0] = c * a0i - s * a1r;
            re[i1] = c * a1r + s * a0i;
            im[i1] = c * a1i - s * a0r;
        }
        __syncthreads();
    };

    // CNOT(ctrl qubit, tgt qubit): swap amplitudes where ctrl bit = 1, over tgt bit.
    auto apply_cnot = [&](int ctrl, int tgt) {
        const int cbit = NQ - 1 - ctrl;
        const int tbit = NQ - 1 - tgt;
        const int lo = cbit < tbit ? cbit : tbit;
        const int hi = cbit < tbit ? tbit : cbit;
        #pragma unroll
        for (int it = 0; it < NSTATES / 4 / THREADS; ++it) {
            const int p  = t + it * THREADS;
            const int x1 = ((p  >> lo) << (lo + 1)) | (p  & ((1 << lo) - 1));
            const int x2 = ((x1 >> hi) << (hi + 1)) | (x1 & ((1 << hi) - 1));
            const int ia = x2 | (1 << cbit);          // ctrl=1, tgt=0
            const int ib = ia | (1 << tbit);          // ctrl=1, tgt=1
            const float tr = re[ia]; re[ia] = re[ib]; re[ib] = tr;
            const float ti = im[ia]; im[ia] = im[ib]; im[ib] = ti;
        }
        __syncthreads();
    };

    // encoding layer: RX(x[b, j]) on qubit j
    for (int j = 0; j < NQ; ++j)
        apply_rx(j, x[b * NQ + j]);

    // variational layers
    for (int l = 0; l < L; ++l) {
        for (int j = 0; j < NQ; ++j)
            apply_rx(j, w[l * NQ + j]);
        for (int j = 0; j < NQ; ++j)
            apply_cnot(j, (j + 1) % NQ);
    }

    // expectations <Z_q> = sum_i |amp_i|^2 * (1 - 2*bit_{NQ-1-q}(i))
    float ex[NQ];
    #pragma unroll
    for (int q = 0; q < NQ; ++q) ex[q] = 0.0f;
    #pragma unroll
    for (int it = 0; it < NSTATES / THREADS; ++it) {
        const int i = t + it * THREADS;
        const float p = re[i] * re[i] + im[i] * im[i];
        #pragma unroll
        for (int q = 0; q < NQ; ++q) {
            const int bit = NQ - 1 - q;
            ex[q] += ((i >> bit) & 1) ? -p : p;
        }
    }
    // 64-lane shuffle reduce, then cross-wave via LDS
    #pragma unroll
    for (int q = 0; q < NQ; ++q) {
        float v = ex[q];
        #pragma unroll
        for (int off = 32; off > 0; off >>= 1)
            v += __shfl_down(v, off, 64);
        ex[q] = v;
    }
    const int wid = t >> 6, lane = t & 63;
    if (lane == 0) {
        #pragma unroll
        for (int q = 0; q < NQ; ++q) wsum[wid][q] = ex[q];
    }
    __syncthreads();
    if (t < NQ) {
        float v = 0.0f;
        #pragma unroll
        for (int k = 0; k < THREADS / 64; ++k) v += wsum[k][t];
        out[b * NQ + t] = v;
    }
}

extern "C" void kernel_launch(void* const* d_in, const int* in_sizes, int n_in,
                              void* d_out, int out_size, void* d_ws, size_t ws_size,
                              hipStream_t stream) {
    const float* x = (const float*)d_in[0];
    const float* w = (const float*)d_in[1];
    float* out = (float*)d_out;
    const int B = in_sizes[0] / NQ;
    const int L = in_sizes[1] / NQ;
    qsim_kernel<<<dim3(B), dim3(THREADS), 0, stream>>>(x, w, out, L);
}

// Round 3
// 70.974 us; speedup vs baseline: 3.1912x; 3.1912x over previous
//
#include <hip/hip_runtime.h>

#define NQ 12
#define NSTATES (1 << NQ)   // 4096

// ---------------------------------------------------------------------------
// Compile-time GF(2) bookkeeping for the fixed L=2 gate schedule.
// State array P (physical). Invariant: P[p] = A[g(p)], g linear over GF(2).
//   logical bit j of g(p) = parity(grow[j] & p);  hcol = columns of g^{-1}.
// CNOT(c,t): grow[11-t] ^= grow[11-c];  hcol[11-c] ^= hcol[11-t].  (no data movement)
// RX(q):     P'[p] = c*P[p] + (-i s)*P[p ^ hcol[11-q]]   (side-independent)
// <Z_q>  :   sum_p |P[p]|^2 * (-1)^parity(grow[11-q] & p)
// ---------------------------------------------------------------------------
struct QPlan { unsigned rx2[NQ]; unsigned sgn[NQ]; };

constexpr QPlan make_plan() {
    QPlan P{};
    unsigned grow[NQ] = {}, hcol[NQ] = {};
    for (int j = 0; j < NQ; ++j) { grow[j] = 1u << j; hcol[j] = 1u << j; }
    // encoding + layer-0 RX happen at h = I (fused into the init product state)
    // CNOT ring #1
    for (int j = 0; j < NQ; ++j) {
        int cb = NQ - 1 - j, tb = NQ - 1 - ((j + 1) % NQ);
        grow[tb] ^= grow[cb]; hcol[cb] ^= hcol[tb];
    }
    for (int q = 0; q < NQ; ++q) P.rx2[q] = hcol[NQ - 1 - q];  // layer-1 RX masks
    // CNOT ring #2
    for (int j = 0; j < NQ; ++j) {
        int cb = NQ - 1 - j, tb = NQ - 1 - ((j + 1) % NQ);
        grow[tb] ^= grow[cb]; hcol[cb] ^= hcol[tb];
    }
    for (int q = 0; q < NQ; ++q) P.sgn[q] = grow[NQ - 1 - q];  // measurement signs
    return P;
}
constexpr QPlan QP = make_plan();

// ---------------------------------------------------------------------------
// Register-resident gates. One wave (64 lanes) holds the full 4096-amp state:
//   layout A: amp(p) at lane = p>>6 (bits 6-11), local k = p&63 (bits 0-5)
//   layout B: amp(p) at lane = p&63,            local k = p>>6
// ---------------------------------------------------------------------------
__device__ __forceinline__ void rx_pair(float& ur, float& ui, float& vr, float& vi,
                                        float c, float s) {
    float nur = fmaf(c, ur,  s * vi);
    float nui = fmaf(c, ui, -s * vr);
    float nvr = fmaf(c, vr,  s * ui);
    float nvi = fmaf(c, vi, -s * ur);
    ur = nur; ui = nui; vr = nvr; vi = nvi;
}

template <int MLOC>
__device__ __forceinline__ void rx_local(float (&ar)[64], float (&ai)[64], float c, float s) {
    #pragma unroll
    for (int ka = 0; ka < 64; ++ka) {
        const int kb = ka ^ MLOC;
        if (ka < kb) rx_pair(ar[ka], ai[ka], ar[kb], ai[kb], c, s);
    }
}

template <int MLOC, int LM>
__device__ __forceinline__ void rx_shfl(float (&ar)[64], float (&ai)[64], float c, float s) {
    if constexpr (MLOC == 0) {
        #pragma unroll
        for (int k = 0; k < 64; ++k) {
            float pr = __shfl_xor(ar[k], LM, 64);
            float pi = __shfl_xor(ai[k], LM, 64);
            ar[k] = fmaf(c, ar[k],  s * pi);
            ai[k] = fmaf(c, ai[k], -s * pr);
        }
    } else {
        #pragma unroll
        for (int ka = 0; ka < 64; ++ka) {
            const int kb = ka ^ MLOC;
            if (ka < kb) {
                float pra = __shfl_xor(ar[kb], LM, 64);
                float pia = __shfl_xor(ai[kb], LM, 64);
                float prb = __shfl_xor(ar[ka], LM, 64);
                float pib = __shfl_xor(ai[ka], LM, 64);
                ar[ka] = fmaf(c, ar[ka],  s * pia);
                ai[ka] = fmaf(c, ai[ka], -s * pra);
                ar[kb] = fmaf(c, ar[kb],  s * pib);
                ai[kb] = fmaf(c, ai[kb], -s * prb);
            }
        }
    }
}

// Dispatch by mask: local part handled in registers, lane part via shuffles.
// Correct for ANY mask; the call-site grouping only affects speed.
template <unsigned MASK>
__device__ __forceinline__ void rx_A(float (&ar)[64], float (&ai)[64], float c, float s) {
    constexpr int MLOC = MASK & 63, LM = (MASK >> 6) & 63;
    if constexpr (LM == 0) rx_local<MLOC>(ar, ai, c, s);
    else                   rx_shfl<MLOC, LM>(ar, ai, c, s);
}
template <unsigned MASK>
__device__ __forceinline__ void rx_B(float (&ar)[64], float (&ai)[64], float c, float s) {
    constexpr int MLOC = (MASK >> 6) & 63, LM = MASK & 63;
    if constexpr (LM == 0) rx_local<MLOC>(ar, ai, c, s);
    else                   rx_shfl<MLOC, LM>(ar, ai, c, s);
}

__global__ __launch_bounds__(64, 2) void qsim_fast(
    const float* __restrict__ x, const float* __restrict__ w, float* __restrict__ out)
{
    __shared__ float tbuf[64 * 65];   // padded transpose buffer (16.6 KB)
    const int b = blockIdx.x;
    const int l = threadIdx.x;

    // Angles: enc+layer0 fused (RX(x)RX(w0) = RX(x+w0)); layer1 separate.
    float c0[NQ], s0[NQ], c2[NQ], s2[NQ];
    #pragma unroll
    for (int j = 0; j < NQ; ++j) {
        __sincosf(0.5f * (x[b * NQ + j] + w[j]), &s0[j], &c0[j]);
        __sincosf(0.5f * w[NQ + j],              &s2[j], &c2[j]);
    }

    // Construct the post-(enc+layer0) product state directly in layout B:
    // amp(p) = prod_q (bit_{11-q}(p) ? sin : cos) * (-i)^popcount(p)
    float ar[64], ai[64];
    {
        float Flo[8], Fhi[8];
        #pragma unroll
        for (int a = 0; a < 8; ++a) {   // k bits 0-2 -> qubits 5,4,3; bits 3-5 -> 2,1,0
            Flo[a] = ((a & 1) ? s0[5] : c0[5]) * ((a & 2) ? s0[4] : c0[4]) * ((a & 4) ? s0[3] : c0[3]);
            Fhi[a] = ((a & 1) ? s0[2] : c0[2]) * ((a & 2) ? s0[1] : c0[1]) * ((a & 4) ? s0[0] : c0[0]);
        }
        float Flane = ((l & 1)  ? s0[11] : c0[11]) * ((l & 2)  ? s0[10] : c0[10])
                    * ((l & 4)  ? s0[9]  : c0[9])  * ((l & 8)  ? s0[8]  : c0[8])
                    * ((l & 16) ? s0[7]  : c0[7])  * ((l & 32) ? s0[6]  : c0[6]);
        const int r = __popc(l);
        float rs[4], is[4];
        #pragma unroll
        for (int cc = 0; cc < 4; ++cc) {  // (-i)^n: 1, -i, -1, i
            int n2 = (r + cc) & 3;
            rs[cc] = (n2 == 0) ? 1.f : ((n2 == 2) ? -1.f : 0.f);
            is[cc] = (n2 == 1) ? -1.f : ((n2 == 3) ? 1.f : 0.f);
        }
        #pragma unroll
        for (int k = 0; k < 64; ++k) {
            float m = Flane * Fhi[k >> 3] * Flo[k & 7];
            const int cls = __builtin_popcount((unsigned)k) & 3;
            ar[k] = m * rs[cls];
            ai[k] = m * is[cls];
        }
    }

    // Layer-1 RX gates whose masks live in bits 6-11: local in layout B.
    rx_B<QP.rx2[0]>(ar, ai, c2[0], s2[0]);
    rx_B<QP.rx2[1]>(ar, ai, c2[1], s2[1]);
    rx_B<QP.rx2[2]>(ar, ai, c2[2], s2[2]);
    rx_B<QP.rx2[3]>(ar, ai, c2[3], s2[3]);
    rx_B<QP.rx2[4]>(ar, ai, c2[4], s2[4]);

    // Transpose B -> A through padded LDS (single wave; syncs are cheap).
    #pragma unroll
    for (int k = 0; k < 64; ++k) tbuf[k * 65 + l] = ar[k];
    __syncthreads();
    #pragma unroll
    for (int k = 0; k < 64; ++k) ar[k] = tbuf[l * 65 + k];
    __syncthreads();
    #pragma unroll
    for (int k = 0; k < 64; ++k) tbuf[k * 65 + l] = ai[k];
    __syncthreads();
    #pragma unroll
    for (int k = 0; k < 64; ++k) ai[k] = tbuf[l * 65 + k];

    // Remaining layer-1 gates: bits 0-5 local in A; the 2 mixed masks take the
    // shuffle path automatically.
    rx_A<QP.rx2[6]>(ar, ai, c2[6], s2[6]);
    rx_A<QP.rx2[7]>(ar, ai, c2[7], s2[7]);
    rx_A<QP.rx2[8]>(ar, ai, c2[8], s2[8]);
    rx_A<QP.rx2[9]>(ar, ai, c2[9], s2[9]);
    rx_A<QP.rx2[10]>(ar, ai, c2[10], s2[10]);
    rx_A<QP.rx2[5]>(ar, ai, c2[5], s2[5]);
    rx_A<QP.rx2[11]>(ar, ai, c2[11], s2[11]);

    // Expectations in layout A: p = (l<<6)|k.
    float ex[NQ];
    #pragma unroll
    for (int q = 0; q < NQ; ++q) ex[q] = 0.f;
    #pragma unroll
    for (int k = 0; k < 64; ++k) {
        float p = fmaf(ar[k], ar[k], ai[k] * ai[k]);
        #pragma unroll
        for (int q = 0; q < NQ; ++q) {
            if (__builtin_popcount(QP.sgn[q] & (unsigned)k) & 1) ex[q] -= p;
            else                                                 ex[q] += p;
        }
    }
    #pragma unroll
    for (int q = 0; q < NQ; ++q) {
        float lsgn = (__popc(((QP.sgn[q] >> 6) & 63u) & (unsigned)l) & 1) ? -1.f : 1.f;
        float v = ex[q] * lsgn;
        #pragma unroll
        for (int off = 32; off >= 1; off >>= 1) v += __shfl_xor(v, off, 64);
        ex[q] = v;
    }
    float o = 0.f;
    #pragma unroll
    for (int q = 0; q < NQ; ++q) o = (l == q) ? ex[q] : o;
    if (l < NQ) out[b * NQ + l] = o;
}

// ---------------------------------------------------------------------------
// Generic fallback (any L) — the verified round-2 LDS kernel.
// ---------------------------------------------------------------------------
__global__ __launch_bounds__(256) void qsim_generic(
    const float* __restrict__ x, const float* __restrict__ w,
    float* __restrict__ out, int L)
{
    __shared__ float re[NSTATES];
    __shared__ float im[NSTATES];
    __shared__ float wsum[4][NQ];
    const int b = blockIdx.x;
    const int t = threadIdx.x;

    for (int i = t; i < NSTATES; i += 256) { re[i] = 0.0f; im[i] = 0.0f; }
    if (t == 0) re[0] = 1.0f;
    __syncthreads();

    auto apply_rx = [&](int q, float theta) {
        const int bit = NQ - 1 - q, mask = 1 << bit;
        const float c = cosf(0.5f * theta), s = sinf(0.5f * theta);
        #pragma unroll
        for (int it = 0; it < NSTATES / 2 / 256; ++it) {
            const int p  = t + it * 256;
            const int i0 = ((p >> bit) << (bit + 1)) | (p & (mask - 1));
            const int i1 = i0 | mask;
            const float a0r = re[i0], a0i = im[i0], a1r = re[i1], a1i = im[i1];
            re[i0] = c * a0r + s * a1i;  im[i0] = c * a0i - s * a1r;
            re[i1] = c * a1r + s * a0i;  im[i1] = c * a1i - s * a0r;
        }
        __syncthreads();
    };
    auto apply_cnot = [&](int ctrl, int tgt) {
        const int cbit = NQ - 1 - ctrl, tbit = NQ - 1 - tgt;
        const int lo = cbit < tbit ? cbit : tbit, hi = cbit < tbit ? tbit : cbit;
        #pragma unroll
        for (int it = 0; it < NSTATES / 4 / 256; ++it) {
            const int p  = t + it * 256;
            const int x1 = ((p  >> lo) << (lo + 1)) | (p  & ((1 << lo) - 1));
            const int x2 = ((x1 >> hi) << (hi + 1)) | (x1 & ((1 << hi) - 1));
            const int ia = x2 | (1 << cbit), ib = ia | (1 << tbit);
            const float tr = re[ia]; re[ia] = re[ib]; re[ib] = tr;
            const float ti = im[ia]; im[ia] = im[ib]; im[ib] = ti;
        }
        __syncthreads();
    };

    for (int j = 0; j < NQ; ++j) apply_rx(j, x[b * NQ + j]);
    for (int l2 = 0; l2 < L; ++l2) {
        for (int j = 0; j < NQ; ++j) apply_rx(j, w[l2 * NQ + j]);
        for (int j = 0; j < NQ; ++j) apply_cnot(j, (j + 1) % NQ);
    }

    float ex[NQ];
    #pragma unroll
    for (int q = 0; q < NQ; ++q) ex[q] = 0.0f;
    #pragma unroll
    for (int it = 0; it < NSTATES / 256; ++it) {
        const int i = t + it * 256;
        const float p = re[i] * re[i] + im[i] * im[i];
        #pragma unroll
        for (int q = 0; q < NQ; ++q) ex[q] += ((i >> (NQ - 1 - q)) & 1) ? -p : p;
    }
    #pragma unroll
    for (int q = 0; q < NQ; ++q) {
        float v = ex[q];
        #pragma unroll
        for (int off = 32; off > 0; off >>= 1) v += __shfl_down(v, off, 64);
        ex[q] = v;
    }
    const int wid = t >> 6, lane = t & 63;
    if (lane == 0) {
        #pragma unroll
        for (int q = 0; q < NQ; ++q) wsum[wid][q] = ex[q];
    }
    __syncthreads();
    if (t < NQ) {
        float v = 0.0f;
        #pragma unroll
        for (int k = 0; k < 4; ++k) v += wsum[k][t];
        out[b * NQ + t] = v;
    }
}

extern "C" void kernel_launch(void* const* d_in, const int* in_sizes, int n_in,
                              void* d_out, int out_size, void* d_ws, size_t ws_size,
                              hipStream_t stream) {
    const float* x = (const float*)d_in[0];
    const float* w = (const float*)d_in[1];
    float* out = (float*)d_out;
    const int B = in_sizes[0] / NQ;
    const int L = in_sizes[1] / NQ;
    if (L == 2) {
        qsim_fast<<<dim3(B), dim3(64), 0, stream>>>(x, w, out);
    } else {
        qsim_generic<<<dim3(B), dim3(256), 0, stream>>>(x, w, out, L);
    }
}

// Round 4
// 69.226 us; speedup vs baseline: 3.2718x; 1.0253x over previous
//
#include <hip/hip_runtime.h>

#define NQ 12
#define NSTATES (1 << NQ)   // 4096

// ---------------------------------------------------------------------------
// GF(2) bookkeeping (HW-verified in R3): CNOTs tracked as a linear index map.
//   layer-1 RX on qubit q  -> XOR-pair rotation with mask rx2[q]
//   <Z_q>                  -> parity sign with mask sgn[q]
// ---------------------------------------------------------------------------
struct QPlan { unsigned rx2[NQ]; unsigned sgn[NQ]; };

constexpr QPlan make_plan() {
    QPlan P{};
    unsigned grow[NQ] = {}, hcol[NQ] = {};
    for (int j = 0; j < NQ; ++j) { grow[j] = 1u << j; hcol[j] = 1u << j; }
    for (int j = 0; j < NQ; ++j) {                       // CNOT ring #1
        int cb = NQ - 1 - j, tb = NQ - 1 - ((j + 1) % NQ);
        grow[tb] ^= grow[cb]; hcol[cb] ^= hcol[tb];
    }
    for (int q = 0; q < NQ; ++q) P.rx2[q] = hcol[NQ - 1 - q];
    for (int j = 0; j < NQ; ++j) {                       // CNOT ring #2
        int cb = NQ - 1 - j, tb = NQ - 1 - ((j + 1) % NQ);
        grow[tb] ^= grow[cb]; hcol[cb] ^= hcol[tb];
    }
    for (int q = 0; q < NQ; ++q) P.sgn[q] = grow[NQ - 1 - q];
    return P;
}
constexpr QPlan QP = make_plan();

// ---------------------------------------------------------------------------
// p-bit role mapping (12 bits -> k:4, lane:6, wave:2), chosen so the triple
// mask rx2[11]=0xC01 is k-local and no gate needs a full-state LDS exchange.
//   k  = {p0, p9, p10, p11}   lane = {p1,p2,p3,p6,p7,p8}   wv = {p4,p5}
// ---------------------------------------------------------------------------
constexpr unsigned kpart(unsigned m) {
    return ((m >> 0) & 1u) | (((m >> 9) & 1u) << 1) | (((m >> 10) & 1u) << 2) | (((m >> 11) & 1u) << 3);
}
constexpr unsigned lpart(unsigned m) {
    return ((m >> 1) & 1u) | (((m >> 2) & 1u) << 1) | (((m >> 3) & 1u) << 2)
         | (((m >> 6) & 1u) << 3) | (((m >> 7) & 1u) << 4) | (((m >> 8) & 1u) << 5);
}
constexpr unsigned wpart(unsigned m) {
    return ((m >> 4) & 1u) | (((m >> 5) & 1u) << 1);
}
constexpr unsigned tpart(unsigned m) { return lpart(m) | (wpart(m) << 6); }

// Compile-time verification of the whole gate classification:
static_assert(kpart(QP.rx2[0]) == 12 && tpart(QP.rx2[0]) == 0, "v-local");
static_assert(kpart(QP.rx2[1]) == 6  && tpart(QP.rx2[1]) == 0, "v-local");
static_assert(kpart(QP.rx2[11]) == 13 && tpart(QP.rx2[11]) == 0, "v-local triple");
static_assert(kpart(QP.rx2[3]) == 0 && wpart(QP.rx2[3]) == 0 && lpart(QP.rx2[3]) == 48, "lane scalar");
static_assert(kpart(QP.rx2[4]) == 0 && wpart(QP.rx2[4]) == 0 && lpart(QP.rx2[4]) == 24, "lane scalar");
static_assert(kpart(QP.rx2[8]) == 0 && wpart(QP.rx2[8]) == 0 && lpart(QP.rx2[8]) == 6,  "lane scalar");
static_assert(kpart(QP.rx2[9]) == 0 && wpart(QP.rx2[9]) == 0 && lpart(QP.rx2[9]) == 3,  "lane scalar");
static_assert(kpart(QP.rx2[5]) == 0 && tpart(QP.rx2[5]) == 136, "cross scalar");
static_assert(kpart(QP.rx2[6]) == 0 && tpart(QP.rx2[6]) == 192, "cross scalar");
static_assert(kpart(QP.rx2[7]) == 0 && tpart(QP.rx2[7]) == 68,  "cross scalar");
static_assert(kpart(QP.rx2[2]) == 2 && lpart(QP.rx2[2]) == 32 && wpart(QP.rx2[2]) == 0, "mixed");
static_assert(kpart(QP.rx2[10]) == 1 && lpart(QP.rx2[10]) == 1 && wpart(QP.rx2[10]) == 0, "mixed");

struct SignPlan { unsigned ks[NQ]; unsigned ts[NQ]; };
constexpr SignPlan make_signs() {
    SignPlan S{};
    for (int q = 0; q < NQ; ++q) { S.ks[q] = kpart(QP.sgn[q]); S.ts[q] = tpart(QP.sgn[q]); }
    return S;
}
constexpr SignPlan SP = make_signs();

// k-local rotation on the shared 16-element k-space vector
template <int KM>
__device__ __forceinline__ void vgate(float (&vr)[16], float (&vi)[16], float c, float s) {
    #pragma unroll
    for (int ka = 0; ka < 16; ++ka) {
        const int kb = ka ^ KM;
        if (ka < kb) {
            float nur = fmaf(c, vr[ka],  s * vi[kb]);
            float nui = fmaf(c, vi[ka], -s * vr[kb]);
            float nvr = fmaf(c, vr[kb],  s * vi[ka]);
            float nvi = fmaf(c, vi[kb], -s * vr[ka]);
            vr[ka] = nur; vi[ka] = nui; vr[kb] = nvr; vi[kb] = nvi;
        }
    }
}

// mixed gate on materialized amps: partner = (lane^LM, k^KM)  [R3-verified form]
template <int KM, int LM>
__device__ __forceinline__ void mixed_gate(float (&ar)[16], float (&ai)[16], float c, float s) {
    #pragma unroll
    for (int ka = 0; ka < 16; ++ka) {
        const int kb = ka ^ KM;
        if (ka < kb) {
            float pra = __shfl_xor(ar[kb], LM, 64);
            float pia = __shfl_xor(ai[kb], LM, 64);
            float prb = __shfl_xor(ar[ka], LM, 64);
            float pib = __shfl_xor(ai[ka], LM, 64);
            ar[ka] = fmaf(c, ar[ka],  s * pia);
            ai[ka] = fmaf(c, ai[ka], -s * pra);
            ar[kb] = fmaf(c, ar[kb],  s * pib);
            ai[kb] = fmaf(c, ai[kb], -s * prb);
        }
    }
}

__global__ __launch_bounds__(256, 4) void qsim_fast(
    const float* __restrict__ x, const float* __restrict__ w, float* __restrict__ out)
{
    __shared__ float xr[256], xi[256];   // 2 KB scalar-exchange buffer
    __shared__ float red[4][NQ];
    const int b = blockIdx.x;
    const int tid = threadIdx.x;
    const int lane = tid & 63;

    // ---- per-thread complex scalar over the 8 tid-mapped qubits ----
    // tid bit i -> p-bit {1,2,3,6,7,8,4,5}[i] -> qubit 11 - pbit
    constexpr int TQ[8] = {10, 9, 8, 5, 4, 3, 7, 6};
    float F = 1.f;
    #pragma unroll
    for (int i = 0; i < 8; ++i) {
        float a = x[b * NQ + TQ[i]] + w[TQ[i]];
        float s, c; __sincosf(0.5f * a, &s, &c);
        F *= ((tid >> i) & 1) ? s : c;
    }
    const int rt = __popc((unsigned)tid) & 3;    // (-i)^rt phase class
    float sr = (rt == 0) ? F : (rt == 2 ? -F : 0.f);
    float si = (rt == 1) ? -F : (rt == 3 ? F : 0.f);

    // ---- k-space vector v[16] (qubits 11,2,1,0), identical in all threads ----
    constexpr int KQ[4] = {11, 2, 1, 0};
    float kc[4], ks[4];
    #pragma unroll
    for (int i = 0; i < 4; ++i) {
        float a = x[b * NQ + KQ[i]] + w[KQ[i]];
        __sincosf(0.5f * a, &ks[i], &kc[i]);
    }
    float vr[16], vi[16];
    #pragma unroll
    for (int k = 0; k < 16; ++k) {
        float g = ((k & 1) ? ks[0] : kc[0]) * ((k & 2) ? ks[1] : kc[1])
                * ((k & 4) ? ks[2] : kc[2]) * ((k & 8) ? ks[3] : kc[3]);
        const int rk = __builtin_popcount((unsigned)k) & 3;
        vr[k] = (rk == 0) ? g : (rk == 2 ? -g : 0.f);
        vi[k] = (rk == 1) ? -g : (rk == 3 ? g : 0.f);
    }

    // ---- v-local gates: rx2[0]=KM12, rx2[1]=KM6, rx2[11]=KM13 ----
    {
        float s, c;
        __sincosf(0.5f * w[NQ + 0],  &s, &c); vgate<12>(vr, vi, c, s);
        __sincosf(0.5f * w[NQ + 1],  &s, &c); vgate<6>(vr, vi, c, s);
        __sincosf(0.5f * w[NQ + 11], &s, &c); vgate<13>(vr, vi, c, s);
    }

    // ---- pure-lane scalar gates: rx2[3]=LM48, rx2[4]=LM24, rx2[8]=LM6, rx2[9]=LM3 ----
    {
        const int LMs[4] = {48, 24, 6, 3};
        const int JJ[4]  = {3, 4, 8, 9};
        #pragma unroll
        for (int i = 0; i < 4; ++i) {
            float s, c; __sincosf(0.5f * w[NQ + JJ[i]], &s, &c);
            float pr = __shfl_xor(sr, LMs[i], 64);
            float pi = __shfl_xor(si, LMs[i], 64);
            sr = fmaf(c, sr,  s * pi);
            si = fmaf(c, si, -s * pr);
        }
    }

    // ---- fused cross-wave scalar gate for rx2[5],rx2[6],rx2[7] (tid offsets 136,192,68) ----
    {
        float s5, c5, s6, c6, s7, c7;
        __sincosf(0.5f * w[NQ + 5], &s5, &c5);
        __sincosf(0.5f * w[NQ + 6], &s6, &c6);
        __sincosf(0.5f * w[NQ + 7], &s7, &c7);
        xr[tid] = sr; xi[tid] = si;
        __syncthreads();
        const float m0 = c5 * c6 * c7;
        const float m5 = s5 * c6 * c7, m6 = c5 * s6 * c7, m7 = c5 * c6 * s7;
        const float m56 = s5 * s6 * c7, m57 = s5 * c6 * s7, m67 = c5 * s6 * s7;
        const float m567 = s5 * s6 * s7;
        float nr = m0 * sr, ni = m0 * si;
        { float pr = xr[tid ^ 136], pi = xi[tid ^ 136]; nr = fmaf( m5, pi, nr); ni = fmaf(-m5, pr, ni); }
        { float pr = xr[tid ^ 192], pi = xi[tid ^ 192]; nr = fmaf( m6, pi, nr); ni = fmaf(-m6, pr, ni); }
        { float pr = xr[tid ^  68], pi = xi[tid ^  68]; nr = fmaf( m7, pi, nr); ni = fmaf(-m7, pr, ni); }
        { float pr = xr[tid ^  72], pi = xi[tid ^  72]; nr = fmaf(-m56, pr, nr); ni = fmaf(-m56, pi, ni); }
        { float pr = xr[tid ^ 204], pi = xi[tid ^ 204]; nr = fmaf(-m57, pr, nr); ni = fmaf(-m57, pi, ni); }
        { float pr = xr[tid ^ 132], pi = xi[tid ^ 132]; nr = fmaf(-m67, pr, nr); ni = fmaf(-m67, pi, ni); }
        { float pr = xr[tid ^  12], pi = xi[tid ^  12]; nr = fmaf(-m567, pi, nr); ni = fmaf( m567, pr, ni); }
        sr = nr; si = ni;
    }

    // ---- materialize the 16 amps, then the 2 mixed gates ----
    float ar[16], ai[16];
    #pragma unroll
    for (int k = 0; k < 16; ++k) {
        ar[k] = sr * vr[k] - si * vi[k];
        ai[k] = sr * vi[k] + si * vr[k];
    }
    {
        float s, c;
        __sincosf(0.5f * w[NQ + 2],  &s, &c); mixed_gate<2, 32>(ar, ai, c, s);
        __sincosf(0.5f * w[NQ + 10], &s, &c); mixed_gate<1, 1>(ar, ai, c, s);
    }

    // ---- expectations: sign = parity(SP.ks[q]&k) ^ parity(SP.ts[q]&tid) ----
    float ex[NQ];
    #pragma unroll
    for (int q = 0; q < NQ; ++q) ex[q] = 0.f;
    #pragma unroll
    for (int k = 0; k < 16; ++k) {
        float p2 = fmaf(ar[k], ar[k], ai[k] * ai[k]);
        #pragma unroll
        for (int q = 0; q < NQ; ++q) {
            if (__builtin_popcount(SP.ks[q] & (unsigned)k) & 1) ex[q] -= p2;
            else                                                ex[q] += p2;
        }
    }
    #pragma unroll
    for (int q = 0; q < NQ; ++q) {
        float v = (__popc(SP.ts[q] & (unsigned)tid) & 1) ? -ex[q] : ex[q];
        #pragma unroll
        for (int off = 32; off >= 1; off >>= 1) v += __shfl_xor(v, off, 64);
        ex[q] = v;
    }
    const int wv = tid >> 6;
    float o = 0.f;
    #pragma unroll
    for (int q = 0; q < NQ; ++q) o = (lane == q) ? ex[q] : o;
    if (lane < NQ) red[wv][lane] = o;
    __syncthreads();
    if (tid < NQ) out[b * NQ + tid] = red[0][tid] + red[1][tid] + red[2][tid] + red[3][tid];
}

// ---------------------------------------------------------------------------
// Generic fallback (any L) — the verified round-2 LDS kernel.
// ---------------------------------------------------------------------------
__global__ __launch_bounds__(256) void qsim_generic(
    const float* __restrict__ x, const float* __restrict__ w,
    float* __restrict__ out, int L)
{
    __shared__ float re[NSTATES];
    __shared__ float im[NSTATES];
    __shared__ float wsum[4][NQ];
    const int b = blockIdx.x;
    const int t = threadIdx.x;

    for (int i = t; i < NSTATES; i += 256) { re[i] = 0.0f; im[i] = 0.0f; }
    if (t == 0) re[0] = 1.0f;
    __syncthreads();

    auto apply_rx = [&](int q, float theta) {
        const int bit = NQ - 1 - q, mask = 1 << bit;
        const float c = cosf(0.5f * theta), s = sinf(0.5f * theta);
        #pragma unroll
        for (int it = 0; it < NSTATES / 2 / 256; ++it) {
            const int p  = t + it * 256;
            const int i0 = ((p >> bit) << (bit + 1)) | (p & (mask - 1));
            const int i1 = i0 | mask;
            const float a0r = re[i0], a0i = im[i0], a1r = re[i1], a1i = im[i1];
            re[i0] = c * a0r + s * a1i;  im[i0] = c * a0i - s * a1r;
            re[i1] = c * a1r + s * a0i;  im[i1] = c * a1i - s * a0r;
        }
        __syncthreads();
    };
    auto apply_cnot = [&](int ctrl, int tgt) {
        const int cbit = NQ - 1 - ctrl, tbit = NQ - 1 - tgt;
        const int lo = cbit < tbit ? cbit : tbit, hi = cbit < tbit ? tbit : cbit;
        #pragma unroll
        for (int it = 0; it < NSTATES / 4 / 256; ++it) {
            const int p  = t + it * 256;
            const int x1 = ((p  >> lo) << (lo + 1)) | (p  & ((1 << lo) - 1));
            const int x2 = ((x1 >> hi) << (hi + 1)) | (x1 & ((1 << hi) - 1));
            const int ia = x2 | (1 << cbit), ib = ia | (1 << tbit);
            const float tr = re[ia]; re[ia] = re[ib]; re[ib] = tr;
            const float ti = im[ia]; im[ia] = im[ib]; im[ib] = ti;
        }
        __syncthreads();
    };

    for (int j = 0; j < NQ; ++j) apply_rx(j, x[b * NQ + j]);
    for (int l2 = 0; l2 < L; ++l2) {
        for (int j = 0; j < NQ; ++j) apply_rx(j, w[l2 * NQ + j]);
        for (int j = 0; j < NQ; ++j) apply_cnot(j, (j + 1) % NQ);
    }

    float ex[NQ];
    #pragma unroll
    for (int q = 0; q < NQ; ++q) ex[q] = 0.0f;
    #pragma unroll
    for (int it = 0; it < NSTATES / 256; ++it) {
        const int i = t + it * 256;
        const float p = re[i] * re[i] + im[i] * im[i];
        #pragma unroll
        for (int q = 0; q < NQ; ++q) ex[q] += ((i >> (NQ - 1 - q)) & 1) ? -p : p;
    }
    #pragma unroll
    for (int q = 0; q < NQ; ++q) {
        float v = ex[q];
        #pragma unroll
        for (int off = 32; off > 0; off >>= 1) v += __shfl_down(v, off, 64);
        ex[q] = v;
    }
    const int wid = t >> 6, lane = t & 63;
    if (lane == 0) {
        #pragma unroll
        for (int q = 0; q < NQ; ++q) wsum[wid][q] = ex[q];
    }
    __syncthreads();
    if (t < NQ) {
        float v = 0.0f;
        #pragma unroll
        for (int k = 0; k < 4; ++k) v += wsum[k][t];
        out[b * NQ + t] = v;
    }
}

extern "C" void kernel_launch(void* const* d_in, const int* in_sizes, int n_in,
                              void* d_out, int out_size, void* d_ws, size_t ws_size,
                              hipStream_t stream) {
    const float* x = (const float*)d_in[0];
    const float* w = (const float*)d_in[1];
    float* out = (float*)d_out;
    const int B = in_sizes[0] / NQ;
    const int L = in_sizes[1] / NQ;
    if (L == 2) {
        qsim_fast<<<dim3(B), dim3(256), 0, stream>>>(x, w, out);
    } else {
        qsim_generic<<<dim3(B), dim3(256), 0, stream>>>(x, w, out, L);
    }
}

// Round 6
// 66.306 us; speedup vs baseline: 3.4158x; 1.0440x over previous
//
#include <hip/hip_runtime.h>

#define NQ 12
#define NSTATES (1 << NQ)   // 4096

// ---------------------------------------------------------------------------
// GF(2) bookkeeping (HW-verified R3/R4): CNOTs tracked as a linear index map.
// ---------------------------------------------------------------------------
struct QPlan { unsigned rx2[NQ]; unsigned sgn[NQ]; };

constexpr QPlan make_plan() {
    QPlan P{};
    unsigned grow[NQ] = {}, hcol[NQ] = {};
    for (int j = 0; j < NQ; ++j) { grow[j] = 1u << j; hcol[j] = 1u << j; }
    for (int j = 0; j < NQ; ++j) {                       // CNOT ring #1
        int cb = NQ - 1 - j, tb = NQ - 1 - ((j + 1) % NQ);
        grow[tb] ^= grow[cb]; hcol[cb] ^= hcol[tb];
    }
    for (int q = 0; q < NQ; ++q) P.rx2[q] = hcol[NQ - 1 - q];
    for (int j = 0; j < NQ; ++j) {                       // CNOT ring #2
        int cb = NQ - 1 - j, tb = NQ - 1 - ((j + 1) % NQ);
        grow[tb] ^= grow[cb]; hcol[cb] ^= hcol[tb];
    }
    for (int q = 0; q < NQ; ++q) P.sgn[q] = grow[NQ - 1 - q];
    return P;
}
constexpr QPlan QP = make_plan();

// p-bit roles: k = {p0,p9,p10,p11}, lane = {p1,p2,p3,p6,p7,p8}, wv = {p4,p5}
constexpr unsigned kpart(unsigned m) {
    return ((m >> 0) & 1u) | (((m >> 9) & 1u) << 1) | (((m >> 10) & 1u) << 2) | (((m >> 11) & 1u) << 3);
}
constexpr unsigned lpart(unsigned m) {
    return ((m >> 1) & 1u) | (((m >> 2) & 1u) << 1) | (((m >> 3) & 1u) << 2)
         | (((m >> 6) & 1u) << 3) | (((m >> 7) & 1u) << 4) | (((m >> 8) & 1u) << 5);
}
constexpr unsigned wpart(unsigned m) {
    return ((m >> 4) & 1u) | (((m >> 5) & 1u) << 1);
}
constexpr unsigned tpart(unsigned m) { return lpart(m) | (wpart(m) << 6); }

static_assert(kpart(QP.rx2[0]) == 12 && tpart(QP.rx2[0]) == 0, "v-local");
static_assert(kpart(QP.rx2[1]) == 6  && tpart(QP.rx2[1]) == 0, "v-local");
static_assert(kpart(QP.rx2[11]) == 13 && tpart(QP.rx2[11]) == 0, "v-local triple");
static_assert(kpart(QP.rx2[3]) == 0 && wpart(QP.rx2[3]) == 0 && lpart(QP.rx2[3]) == 48, "lane scalar");
static_assert(kpart(QP.rx2[4]) == 0 && wpart(QP.rx2[4]) == 0 && lpart(QP.rx2[4]) == 24, "lane scalar");
static_assert(kpart(QP.rx2[8]) == 0 && wpart(QP.rx2[8]) == 0 && lpart(QP.rx2[8]) == 6,  "lane scalar");
static_assert(kpart(QP.rx2[9]) == 0 && wpart(QP.rx2[9]) == 0 && lpart(QP.rx2[9]) == 3,  "lane scalar");
static_assert(kpart(QP.rx2[5]) == 0 && tpart(QP.rx2[5]) == 136, "cross scalar");
static_assert(kpart(QP.rx2[6]) == 0 && tpart(QP.rx2[6]) == 192, "cross scalar");
static_assert(kpart(QP.rx2[7]) == 0 && tpart(QP.rx2[7]) == 68,  "cross scalar");
static_assert(kpart(QP.rx2[2]) == 2 && lpart(QP.rx2[2]) == 32 && wpart(QP.rx2[2]) == 0, "mixed");
static_assert(kpart(QP.rx2[10]) == 1 && lpart(QP.rx2[10]) == 1 && wpart(QP.rx2[10]) == 0, "mixed");

struct SignPlan { unsigned ks[NQ]; unsigned ts[NQ]; };
constexpr SignPlan make_signs() {
    SignPlan S{};
    for (int q = 0; q < NQ; ++q) { S.ks[q] = kpart(QP.sgn[q]); S.ts[q] = tpart(QP.sgn[q]); }
    return S;
}
constexpr SignPlan SP = make_signs();

// ---------------------------------------------------------------------------
// f16x2 packing for cross-lane payloads (halves DS-op count; error << thresh)
// NOTE: __builtin_amdgcn_cvt_pkrtz returns __fp16 ext_vector_type(2) — use
// exactly that type (R5 compile fix).
// ---------------------------------------------------------------------------
typedef __fp16 half2_t __attribute__((ext_vector_type(2)));
__device__ __forceinline__ int pk(float a, float b) {
    half2_t h = __builtin_amdgcn_cvt_pkrtz(a, b);
    return __builtin_bit_cast(int, h);
}
__device__ __forceinline__ void upk(int u, float& a, float& b) {
    half2_t h = __builtin_bit_cast(half2_t, u);
    a = (float)h[0]; b = (float)h[1];
}

// k-local rotation on the 16-element k-space vector
template <int KM>
__device__ __forceinline__ void vgate(float (&vr)[16], float (&vi)[16], float c, float s) {
    #pragma unroll
    for (int ka = 0; ka < 16; ++ka) {
        const int kb = ka ^ KM;
        if (ka < kb) {
            float nur = fmaf(c, vr[ka],  s * vi[kb]);
            float nui = fmaf(c, vi[ka], -s * vr[kb]);
            float nvr = fmaf(c, vr[kb],  s * vi[ka]);
            float nvi = fmaf(c, vi[kb], -s * vr[ka]);
            vr[ka] = nur; vi[ka] = nui; vr[kb] = nvr; vi[kb] = nvi;
        }
    }
}

// mixed gate with f16-packed partner exchange: partner = (lane^LM, k^KM)
template <int KM, int LM>
__device__ __forceinline__ void mixed_gate(float (&ar)[16], float (&ai)[16], float c, float s) {
    #pragma unroll
    for (int ka = 0; ka < 16; ++ka) {
        const int kb = ka ^ KM;
        if (ka < kb) {
            int ua = __shfl_xor(pk(ar[kb], ai[kb]), LM, 64);  // partner's kb pair
            int ub = __shfl_xor(pk(ar[ka], ai[ka]), LM, 64);  // partner's ka pair
            float pra, pia, prb, pib;
            upk(ua, pra, pia); upk(ub, prb, pib);
            ar[ka] = fmaf(c, ar[ka],  s * pia);
            ai[ka] = fmaf(c, ai[ka], -s * pra);
            ar[kb] = fmaf(c, ar[kb],  s * pib);
            ai[kb] = fmaf(c, ai[kb], -s * prb);
        }
    }
}

#define PAD_STRIDE 257
#define SMEM2_OFF  (NQ * PAD_STRIDE)         // 3084
#define SMEM_TOTAL (SMEM2_OFF + 192)         // 3276 floats = 13.1 KB

__global__ __launch_bounds__(256, 4) void qsim_fast(
    const float* __restrict__ x, const float* __restrict__ w, float* __restrict__ out)
{
    __shared__ __align__(16) float smem[SMEM_TOTAL];
    const int b = blockIdx.x;
    const int tid = threadIdx.x;

    // ---- per-thread complex scalar over the 8 tid-mapped qubits ----
    constexpr int TQ[8] = {10, 9, 8, 5, 4, 3, 7, 6};
    float F = 1.f;
    #pragma unroll
    for (int i = 0; i < 8; ++i) {
        float a = x[b * NQ + TQ[i]] + w[TQ[i]];
        float s, c; __sincosf(0.5f * a, &s, &c);
        F *= ((tid >> i) & 1) ? s : c;
    }
    const int rt = __popc((unsigned)tid) & 3;    // (-i)^rt phase class
    float sr = (rt == 0) ? F : (rt == 2 ? -F : 0.f);
    float si = (rt == 1) ? -F : (rt == 3 ? F : 0.f);

    // ---- k-space vector v[16] (qubits 11,2,1,0), same in all threads ----
    constexpr int KQ[4] = {11, 2, 1, 0};
    float kc[4], ks[4];
    #pragma unroll
    for (int i = 0; i < 4; ++i) {
        float a = x[b * NQ + KQ[i]] + w[KQ[i]];
        __sincosf(0.5f * a, &ks[i], &kc[i]);
    }
    float vr[16], vi[16];
    #pragma unroll
    for (int k = 0; k < 16; ++k) {
        float g = ((k & 1) ? ks[0] : kc[0]) * ((k & 2) ? ks[1] : kc[1])
                * ((k & 4) ? ks[2] : kc[2]) * ((k & 8) ? ks[3] : kc[3]);
        const int rk = __builtin_popcount((unsigned)k) & 3;
        vr[k] = (rk == 0) ? g : (rk == 2 ? -g : 0.f);
        vi[k] = (rk == 1) ? -g : (rk == 3 ? g : 0.f);
    }

    // ---- v-local gates ----
    {
        float s, c;
        __sincosf(0.5f * w[NQ + 0],  &s, &c); vgate<12>(vr, vi, c, s);
        __sincosf(0.5f * w[NQ + 1],  &s, &c); vgate<6>(vr, vi, c, s);
        __sincosf(0.5f * w[NQ + 11], &s, &c); vgate<13>(vr, vi, c, s);
    }

    // ---- pure-lane scalar gates (packed shuffles) ----
    {
        const int LMs[4] = {48, 24, 6, 3};
        const int JJ[4]  = {3, 4, 8, 9};
        #pragma unroll
        for (int i = 0; i < 4; ++i) {
            float s, c; __sincosf(0.5f * w[NQ + JJ[i]], &s, &c);
            float pr, pi;
            upk(__shfl_xor(pk(sr, si), LMs[i], 64), pr, pi);
            sr = fmaf(c, sr,  s * pi);
            si = fmaf(c, si, -s * pr);
        }
    }

    // ---- fused cross-wave scalar gate (rx2[5,6,7]; tid offsets 136,192,68) ----
    {
        float s5, c5, s6, c6, s7, c7;
        __sincosf(0.5f * w[NQ + 5], &s5, &c5);
        __sincosf(0.5f * w[NQ + 6], &s6, &c6);
        __sincosf(0.5f * w[NQ + 7], &s7, &c7);
        int* xpk = reinterpret_cast<int*>(smem);
        xpk[tid] = pk(sr, si);
        __syncthreads();
        const float m0 = c5 * c6 * c7;
        const float m5 = s5 * c6 * c7, m6 = c5 * s6 * c7, m7 = c5 * c6 * s7;
        const float m56 = s5 * s6 * c7, m57 = s5 * c6 * s7, m67 = c5 * s6 * s7;
        const float m567 = s5 * s6 * s7;
        float nr = m0 * sr, ni = m0 * si;
        float pr, pi;
        upk(xpk[tid ^ 136], pr, pi); nr = fmaf( m5, pi, nr); ni = fmaf(-m5, pr, ni);
        upk(xpk[tid ^ 192], pr, pi); nr = fmaf( m6, pi, nr); ni = fmaf(-m6, pr, ni);
        upk(xpk[tid ^  68], pr, pi); nr = fmaf( m7, pi, nr); ni = fmaf(-m7, pr, ni);
        upk(xpk[tid ^  72], pr, pi); nr = fmaf(-m56, pr, nr); ni = fmaf(-m56, pi, ni);
        upk(xpk[tid ^ 204], pr, pi); nr = fmaf(-m57, pr, nr); ni = fmaf(-m57, pi, ni);
        upk(xpk[tid ^ 132], pr, pi); nr = fmaf(-m67, pr, nr); ni = fmaf(-m67, pi, ni);
        upk(xpk[tid ^  12], pr, pi); nr = fmaf(-m567, pi, nr); ni = fmaf( m567, pr, ni);
        sr = nr; si = ni;
    }

    // ---- materialize 16 amps, 2 mixed gates ----
    float ar[16], ai[16];
    #pragma unroll
    for (int k = 0; k < 16; ++k) {
        ar[k] = sr * vr[k] - si * vi[k];
        ai[k] = sr * vi[k] + si * vr[k];
    }
    {
        float s, c;
        __sincosf(0.5f * w[NQ + 2],  &s, &c); mixed_gate<2, 32>(ar, ai, c, s);
        __sincosf(0.5f * w[NQ + 10], &s, &c); mixed_gate<1, 1>(ar, ai, c, s);
    }

    // ---- |amp|^2 then 16-point WHT: W[m] = sum_k (-1)^<m,k> p2[k] ----
    float W[16];
    #pragma unroll
    for (int k = 0; k < 16; ++k) W[k] = fmaf(ar[k], ar[k], ai[k] * ai[k]);
    #pragma unroll
    for (int m = 1; m < 16; m <<= 1) {
        #pragma unroll
        for (int k = 0; k < 16; ++k) {
            if (!(k & m)) {
                float a = W[k], bb = W[k | m];
                W[k] = a + bb; W[k | m] = a - bb;
            }
        }
    }

    __syncthreads();   // protect exchange-buffer region before reuse

    // ---- stage 1: per-thread signed values -> LDS [q][tid] (pad 257) ----
    #pragma unroll
    for (int q = 0; q < NQ; ++q) {
        float v = W[SP.ks[q]];
        if (__popc(SP.ts[q] & (unsigned)tid) & 1) v = -v;
        smem[q * PAD_STRIDE + tid] = v;
    }
    __syncthreads();

    // ---- stage 2: 192 workers, each sums 16 (rotated order, q-padded) ----
    if (tid < 192) {
        const int q = tid >> 4, c = tid & 15;
        const int base = q * PAD_STRIDE + c * 16;
        float sum = 0.f;
        #pragma unroll
        for (int jj = 0; jj < 16; ++jj)
            sum += smem[base + ((jj + c) & 15)];
        smem[SMEM2_OFF + tid] = sum;
    }
    __syncthreads();

    // ---- stage 3: 12 threads, 4x float4 reads each ----
    if (tid < NQ) {
        const float4* p = reinterpret_cast<const float4*>(&smem[SMEM2_OFF + 16 * tid]);
        float4 a0 = p[0], a1 = p[1], a2 = p[2], a3 = p[3];
        float v = (a0.x + a0.y + a0.z + a0.w) + (a1.x + a1.y + a1.z + a1.w)
                + (a2.x + a2.y + a2.z + a2.w) + (a3.x + a3.y + a3.z + a3.w);
        out[b * NQ + tid] = v;
    }
}

// ---------------------------------------------------------------------------
// Generic fallback (any L) — the verified round-2 LDS kernel.
// ---------------------------------------------------------------------------
__global__ __launch_bounds__(256) void qsim_generic(
    const float* __restrict__ x, const float* __restrict__ w,
    float* __restrict__ out, int L)
{
    __shared__ float re[NSTATES];
    __shared__ float im[NSTATES];
    __shared__ float wsum[4][NQ];
    const int b = blockIdx.x;
    const int t = threadIdx.x;

    for (int i = t; i < NSTATES; i += 256) { re[i] = 0.0f; im[i] = 0.0f; }
    if (t == 0) re[0] = 1.0f;
    __syncthreads();

    auto apply_rx = [&](int q, float theta) {
        const int bit = NQ - 1 - q, mask = 1 << bit;
        const float c = cosf(0.5f * theta), s = sinf(0.5f * theta);
        #pragma unroll
        for (int it = 0; it < NSTATES / 2 / 256; ++it) {
            const int p  = t + it * 256;
            const int i0 = ((p >> bit) << (bit + 1)) | (p & (mask - 1));
            const int i1 = i0 | mask;
            const float a0r = re[i0], a0i = im[i0], a1r = re[i1], a1i = im[i1];
            re[i0] = c * a0r + s * a1i;  im[i0] = c * a0i - s * a1r;
            re[i1] = c * a1r + s * a0i;  im[i1] = c * a1i - s * a0r;
        }
        __syncthreads();
    };
    auto apply_cnot = [&](int ctrl, int tgt) {
        const int cbit = NQ - 1 - ctrl, tbit = NQ - 1 - tgt;
        const int lo = cbit < tbit ? cbit : tbit, hi = cbit < tbit ? tbit : cbit;
        #pragma unroll
        for (int it = 0; it < NSTATES / 4 / 256; ++it) {
            const int p  = t + it * 256;
            const int x1 = ((p  >> lo) << (lo + 1)) | (p  & ((1 << lo) - 1));
            const int x2 = ((x1 >> hi) << (hi + 1)) | (x1 & ((1 << hi) - 1));
            const int ia = x2 | (1 << cbit), ib = ia | (1 << tbit);
            const float tr = re[ia]; re[ia] = re[ib]; re[ib] = tr;
            const float ti = im[ia]; im[ia] = im[ib]; im[ib] = ti;
        }
        __syncthreads();
    };

    for (int j = 0; j < NQ; ++j) apply_rx(j, x[b * NQ + j]);
    for (int l2 = 0; l2 < L; ++l2) {
        for (int j = 0; j < NQ; ++j) apply_rx(j, w[l2 * NQ + j]);
        for (int j = 0; j < NQ; ++j) apply_cnot(j, (j + 1) % NQ);
    }

    float ex[NQ];
    #pragma unroll
    for (int q = 0; q < NQ; ++q) ex[q] = 0.0f;
    #pragma unroll
    for (int it = 0; it < NSTATES / 256; ++it) {
        const int i = t + it * 256;
        const float p = re[i] * re[i] + im[i] * im[i];
        #pragma unroll
        for (int q = 0; q < NQ; ++q) ex[q] += ((i >> (NQ - 1 - q)) & 1) ? -p : p;
    }
    #pragma unroll
    for (int q = 0; q < NQ; ++q) {
        float v = ex[q];
        #pragma unroll
        for (int off = 32; off > 0; off >>= 1) v += __shfl_down(v, off, 64);
        ex[q] = v;
    }
    const int wid = t >> 6, lane = t & 63;
    if (lane == 0) {
        #pragma unroll
        for (int q = 0; q < NQ; ++q) wsum[wid][q] = ex[q];
    }
    __syncthreads();
    if (t < NQ) {
        float v = 0.0f;
        #pragma unroll
        for (int k = 0; k < 4; ++k) v += wsum[k][t];
        out[b * NQ + t] = v;
    }
}

extern "C" void kernel_launch(void* const* d_in, const int* in_sizes, int n_in,
                              void* d_out, int out_size, void* d_ws, size_t ws_size,
                              hipStream_t stream) {
    const float* x = (const float*)d_in[0];
    const float* w = (const float*)d_in[1];
    float* out = (float*)d_out;
    const int B = in_sizes[0] / NQ;
    const int L = in_sizes[1] / NQ;
    if (L == 2) {
        qsim_fast<<<dim3(B), dim3(256), 0, stream>>>(x, w, out);
    } else {
        qsim_generic<<<dim3(B), dim3(256), 0, stream>>>(x, w, out, L);
    }
}

// Round 7
// 57.893 us; speedup vs baseline: 3.9123x; 1.1453x over previous
//
#include <hip/hip_runtime.h>

#define NQ 12
#define NSTATES (1 << NQ)   // 4096

// ---------------------------------------------------------------------------
// GF(2) bookkeeping (HW-verified R3/R4/R6): CNOTs tracked as linear index map.
//   layer-1 RX gate j: P' = c*P + (-i s)*P[p ^ rx2[j]]
//   <Z_q> = sum_p |P[p]|^2 * (-1)^parity(sgn[q] & p)
// ---------------------------------------------------------------------------
struct QPlan { unsigned rx2[NQ]; unsigned sgn[NQ]; };

constexpr QPlan make_plan() {
    QPlan P{};
    unsigned grow[NQ] = {}, hcol[NQ] = {};
    for (int j = 0; j < NQ; ++j) { grow[j] = 1u << j; hcol[j] = 1u << j; }
    for (int j = 0; j < NQ; ++j) {                       // CNOT ring #1
        int cb = NQ - 1 - j, tb = NQ - 1 - ((j + 1) % NQ);
        grow[tb] ^= grow[cb]; hcol[cb] ^= hcol[tb];
    }
    for (int q = 0; q < NQ; ++q) P.rx2[q] = hcol[NQ - 1 - q];
    for (int j = 0; j < NQ; ++j) {                       // CNOT ring #2
        int cb = NQ - 1 - j, tb = NQ - 1 - ((j + 1) % NQ);
        grow[tb] ^= grow[cb]; hcol[cb] ^= hcol[tb];
    }
    for (int q = 0; q < NQ; ++q) P.sgn[q] = grow[NQ - 1 - q];
    return P;
}
constexpr QPlan QP = make_plan();

// ---------------------------------------------------------------------------
// Ring-cut decomposition: arcs A = {p0..p5}, B = {p6..p11}.
// 10 gates are intra-arc; 2 gates cross (j=5: A:0x20/B:0x01, j=11: A:0x01/B:0x30).
// Pin the entire decomposition at compile time against QP:
// ---------------------------------------------------------------------------
static_assert(QP.rx2[6] == 0x030 && QP.rx2[7] == 0x018 && QP.rx2[8] == 0x00C &&
              QP.rx2[9] == 0x006 && QP.rx2[10] == 0x003, "A-intra gates");
static_assert(QP.rx2[0] == 0xC00 && QP.rx2[1] == 0x600 && QP.rx2[2] == 0x300 &&
              QP.rx2[3] == 0x180 && QP.rx2[4] == 0x0C0, "B-intra gates");
static_assert(QP.rx2[5] == 0x060 && QP.rx2[11] == 0xC01, "cut gates");

// Expectation plan: gA/gB sign masks per q; beta parity bits select which
// entanglement cross-terms survive (derived from ma=0x20*t1^0x01*t2,
// mb=0x01*t1^0x30*t2 offset structure).
struct EPlan { unsigned gA[NQ]; unsigned gB[NQ]; unsigned b1mask; unsigned b2mask; };
constexpr EPlan make_eplan() {
    EPlan E{}; E.b1mask = 0; E.b2mask = 0;
    for (int q = 0; q < NQ; ++q) {
        unsigned M = QP.sgn[q];
        E.gA[q] = M & 63u;
        E.gB[q] = (M >> 6) & 63u;
        unsigned b1 = ((E.gA[q] >> 5) & 1u) ^ (E.gB[q] & 1u);
        unsigned b2 = (E.gA[q] & 1u) ^ ((E.gB[q] >> 4) & 1u) ^ ((E.gB[q] >> 5) & 1u);
        E.b1mask |= b1 << q;
        E.b2mask |= b2 << q;
    }
    return E;
}
constexpr EPlan EP = make_eplan();

// ---------------------------------------------------------------------------
// One WAVE per batch element: lane l holds A(l) and B(l) (complex scalars).
// No LDS, no barriers. 4 waves (4 batch elements) per 256-thread block.
// ---------------------------------------------------------------------------
__global__ __launch_bounds__(256) void qsim_fast(
    const float* __restrict__ x, const float* __restrict__ w,
    float* __restrict__ out, int B)
{
    const int wv   = threadIdx.x >> 6;
    const int lane = threadIdx.x & 63;
    const int b    = blockIdx.x * 4 + wv;
    if (b >= B) return;

    // ---- angles: enc+layer0 fused (RX(x)RX(w0)=RX(x+w0)); layer1 separate ----
    float c0[NQ], s0[NQ], c1[NQ], s1[NQ];
    #pragma unroll
    for (int j = 0; j < NQ; ++j) {
        __sincosf(0.5f * (x[b * NQ + j] + w[j]), &s0[j], &c0[j]);
        __sincosf(0.5f * w[NQ + j],              &s1[j], &c1[j]);
    }

    // ---- product-state factors: A over qubits {11..6}, B over {5..0} ----
    // factor(l) = (-i)^popc(l) * prod_i (l_i ? sin : cos)
    float FA = 1.f, FB = 1.f;
    #pragma unroll
    for (int i = 0; i < 6; ++i) {
        FA *= ((lane >> i) & 1) ? s0[11 - i] : c0[11 - i];
        FB *= ((lane >> i) & 1) ? s0[5 - i]  : c0[5 - i];
    }
    const int r = __popc((unsigned)lane) & 3;   // (-i)^r: 1,-i,-1,i
    float aR = (r == 0) ? FA : (r == 2 ? -FA : 0.f);
    float aI = (r == 1) ? -FA : (r == 3 ? FA : 0.f);
    float bR = (r == 0) ? FB : (r == 2 ? -FB : 0.f);
    float bI = (r == 1) ? -FB : (r == 3 ? FB : 0.f);

    // ---- intra-arc gates: z' = c*z - i*s*z(l^m) ----
    auto sgate = [&](float& zr, float& zi, int m, float c, float s) {
        float pr = __shfl_xor(zr, m, 64);
        float pi = __shfl_xor(zi, m, 64);
        zr = fmaf(c, zr,  s * pi);
        zi = fmaf(c, zi, -s * pr);
    };
    sgate(aR, aI, 0x30, c1[6],  s1[6]);
    sgate(aR, aI, 0x18, c1[7],  s1[7]);
    sgate(aR, aI, 0x0C, c1[8],  s1[8]);
    sgate(aR, aI, 0x06, c1[9],  s1[9]);
    sgate(aR, aI, 0x03, c1[10], s1[10]);
    sgate(bR, bI, 0x30, c1[0],  s1[0]);
    sgate(bR, bI, 0x18, c1[1],  s1[1]);
    sgate(bR, bI, 0x0C, c1[2],  s1[2]);
    sgate(bR, bI, 0x06, c1[3],  s1[3]);
    sgate(bR, bI, 0x03, c1[4],  s1[4]);

    // ---- correlators T(delta,g) = sum_u (-1)^{g.u} V(u^delta) conj(V(u)),
    //      computed for ALL g at once via cross-lane 64-pt WHT (result at lane g)
    auto corr = [&](float zr, float zi, int delta, float& hr, float& hi) {
        float pr = __shfl_xor(zr, delta, 64);
        float pi = __shfl_xor(zi, delta, 64);
        hr = pr * zr + pi * zi;
        hi = pi * zr - pr * zi;
    };
    auto whtc = [&](float& hr, float& hi) {
        #pragma unroll
        for (int m = 1; m < 64; m <<= 1) {
            float vr = __shfl_xor(hr, m, 64);
            float vi = __shfl_xor(hi, m, 64);
            const bool hib = lane & m;
            hr = hib ? vr - hr : hr + vr;
            hi = hib ? vi - hi : hi + vi;
        }
    };
    auto whtr = [&](float& hr) {
        #pragma unroll
        for (int m = 1; m < 64; m <<= 1) {
            float vr = __shfl_xor(hr, m, 64);
            hr = (lane & m) ? vr - hr : hr + vr;
        }
    };

    float TA0r = aR * aR + aI * aI;                 whtr(TA0r);
    float TA1r, TA1i;   corr(aR, aI, 0x01, TA1r, TA1i);   whtc(TA1r, TA1i);
    float TA20r, TA20i; corr(aR, aI, 0x20, TA20r, TA20i); whtc(TA20r, TA20i);
    float TA21r, TA21i; corr(aR, aI, 0x21, TA21r, TA21i); whtc(TA21r, TA21i);

    float TB0r = bR * bR + bI * bI;                 whtr(TB0r);
    float TB01r, TB01i; corr(bR, bI, 0x01, TB01r, TB01i); whtc(TB01r, TB01i);
    float TB30r, TB30i; corr(bR, bI, 0x30, TB30r, TB30i); whtc(TB30r, TB30i);
    float TB31r, TB31i; corr(bR, bI, 0x31, TB31r, TB31i); whtc(TB31r, TB31i);

    // ---- assembly: lane q (<12) computes <Z_q> ----
    unsigned gA = 0, gB = 0;
    #pragma unroll
    for (int qq = 0; qq < NQ; ++qq) {
        if (lane == qq) { gA = EP.gA[qq]; gB = EP.gB[qq]; }
    }
    const bool be1 = (EP.b1mask >> lane) & 1;   // lanes >= 12 read 0 (no store)
    const bool be2 = (EP.b2mask >> lane) & 1;

    // fetch T values from holder lanes (ds_bpermute, per-lane constant src)
    float ta0  = __shfl(TA0r,  (int)gA, 64);
    float ta1r = __shfl(TA1r,  (int)gA, 64),  ta1i = __shfl(TA1i,  (int)gA, 64);
    float ta2r = __shfl(TA20r, (int)gA, 64),  ta2i = __shfl(TA20i, (int)gA, 64);
    float ta3r = __shfl(TA21r, (int)gA, 64),  ta3i = __shfl(TA21i, (int)gA, 64);
    float tb0  = __shfl(TB0r,  (int)gB, 64);
    float tb1r = __shfl(TB30r, (int)gB, 64),  tb1i = __shfl(TB30i, (int)gB, 64);
    float tb2r = __shfl(TB01r, (int)gB, 64),  tb2i = __shfl(TB01i, (int)gB, 64);
    float tb3r = __shfl(TB31r, (int)gB, 64),  tb3i = __shfl(TB31i, (int)gB, 64);

    // entanglement coefficients: cos/sin of the FULL cut angles
    const float ch5  = c1[5]  * c1[5]  - s1[5]  * s1[5];
    const float sh5  = 2.f * c1[5]  * s1[5];
    const float ch11 = c1[11] * c1[11] - s1[11] * s1[11];
    const float sh11 = 2.f * c1[11] * s1[11];

    const float CA = be1 ? ch5  : 1.f;
    const float CB = be2 ? ch11 : 1.f;
    float res = CA * CB * ta0 * tb0;
    if (be2) res += CA * sh11 * (ta1r * tb1i + ta1i * tb1r);           // Im(TA1*TB30)
    if (be1) res += CB * sh5  * (ta2r * tb2i + ta2i * tb2r);           // Im(TA20*TB01)
    if (be1 && be2) res -= sh5 * sh11 * (ta3r * tb3r - ta3i * tb3i);   // Re(TA21*TB31)

    if (lane < NQ) out[b * NQ + lane] = res;
}

// ---------------------------------------------------------------------------
// Generic fallback (any L) — the verified round-2 LDS kernel.
// ---------------------------------------------------------------------------
__global__ __launch_bounds__(256) void qsim_generic(
    const float* __restrict__ x, const float* __restrict__ w,
    float* __restrict__ out, int L)
{
    __shared__ float re[NSTATES];
    __shared__ float im[NSTATES];
    __shared__ float wsum[4][NQ];
    const int b = blockIdx.x;
    const int t = threadIdx.x;

    for (int i = t; i < NSTATES; i += 256) { re[i] = 0.0f; im[i] = 0.0f; }
    if (t == 0) re[0] = 1.0f;
    __syncthreads();

    auto apply_rx = [&](int q, float theta) {
        const int bit = NQ - 1 - q, mask = 1 << bit;
        const float c = cosf(0.5f * theta), s = sinf(0.5f * theta);
        #pragma unroll
        for (int it = 0; it < NSTATES / 2 / 256; ++it) {
            const int p  = t + it * 256;
            const int i0 = ((p >> bit) << (bit + 1)) | (p & (mask - 1));
            const int i1 = i0 | mask;
            const float a0r = re[i0], a0i = im[i0], a1r = re[i1], a1i = im[i1];
            re[i0] = c * a0r + s * a1i;  im[i0] = c * a0i - s * a1r;
            re[i1] = c * a1r + s * a0i;  im[i1] = c * a1i - s * a0r;
        }
        __syncthreads();
    };
    auto apply_cnot = [&](int ctrl, int tgt) {
        const int cbit = NQ - 1 - ctrl, tbit = NQ - 1 - tgt;
        const int lo = cbit < tbit ? cbit : tbit, hi = cbit < tbit ? tbit : cbit;
        #pragma unroll
        for (int it = 0; it < NSTATES / 4 / 256; ++it) {
            const int p  = t + it * 256;
            const int x1 = ((p  >> lo) << (lo + 1)) | (p  & ((1 << lo) - 1));
            const int x2 = ((x1 >> hi) << (hi + 1)) | (x1 & ((1 << hi) - 1));
            const int ia = x2 | (1 << cbit), ib = ia | (1 << tbit);
            const float tr = re[ia]; re[ia] = re[ib]; re[ib] = tr;
            const float ti = im[ia]; im[ia] = im[ib]; im[ib] = ti;
        }
        __syncthreads();
    };

    for (int j = 0; j < NQ; ++j) apply_rx(j, x[b * NQ + j]);
    for (int l2 = 0; l2 < L; ++l2) {
        for (int j = 0; j < NQ; ++j) apply_rx(j, w[l2 * NQ + j]);
        for (int j = 0; j < NQ; ++j) apply_cnot(j, (j + 1) % NQ);
    }

    float ex[NQ];
    #pragma unroll
    for (int q = 0; q < NQ; ++q) ex[q] = 0.0f;
    #pragma unroll
    for (int it = 0; it < NSTATES / 256; ++it) {
        const int i = t + it * 256;
        const float p = re[i] * re[i] + im[i] * im[i];
        #pragma unroll
        for (int q = 0; q < NQ; ++q) ex[q] += ((i >> (NQ - 1 - q)) & 1) ? -p : p;
    }
    #pragma unroll
    for (int q = 0; q < NQ; ++q) {
        float v = ex[q];
        #pragma unroll
        for (int off = 32; off > 0; off >>= 1) v += __shfl_down(v, off, 64);
        ex[q] = v;
    }
    const int wid = t >> 6, lane = t & 63;
    if (lane == 0) {
        #pragma unroll
        for (int q = 0; q < NQ; ++q) wsum[wid][q] = ex[q];
    }
    __syncthreads();
    if (t < NQ) {
        float v = 0.0f;
        #pragma unroll
        for (int k = 0; k < 4; ++k) v += wsum[k][t];
        out[b * NQ + t] = v;
    }
}

extern "C" void kernel_launch(void* const* d_in, const int* in_sizes, int n_in,
                              void* d_out, int out_size, void* d_ws, size_t ws_size,
                              hipStream_t stream) {
    const float* x = (const float*)d_in[0];
    const float* w = (const float*)d_in[1];
    float* out = (float*)d_out;
    const int B = in_sizes[0] / NQ;
    const int L = in_sizes[1] / NQ;
    if (L == 2) {
        qsim_fast<<<dim3((B + 3) / 4), dim3(256), 0, stream>>>(x, w, out, B);
    } else {
        qsim_generic<<<dim3(B), dim3(256), 0, stream>>>(x, w, out, L);
    }
}

// Round 8
// 57.138 us; speedup vs baseline: 3.9640x; 1.0132x over previous
//
#include <hip/hip_runtime.h>

#define NQ 12
#define NSTATES (1 << NQ)   // 4096

// ---------------------------------------------------------------------------
// GF(2) bookkeeping (HW-verified R3/R4/R6/R7): CNOTs as a linear index map.
//   layer-1 RX gate j: P' = c*P + (-i s)*P[p ^ rx2[j]]
//   <Z_q> = sum_p |P[p]|^2 * (-1)^parity(sgn[q] & p)
// ---------------------------------------------------------------------------
struct QPlan { unsigned rx2[NQ]; unsigned sgn[NQ]; };

constexpr QPlan make_plan() {
    QPlan P{};
    unsigned grow[NQ] = {}, hcol[NQ] = {};
    for (int j = 0; j < NQ; ++j) { grow[j] = 1u << j; hcol[j] = 1u << j; }
    for (int j = 0; j < NQ; ++j) {                       // CNOT ring #1
        int cb = NQ - 1 - j, tb = NQ - 1 - ((j + 1) % NQ);
        grow[tb] ^= grow[cb]; hcol[cb] ^= hcol[tb];
    }
    for (int q = 0; q < NQ; ++q) P.rx2[q] = hcol[NQ - 1 - q];
    for (int j = 0; j < NQ; ++j) {                       // CNOT ring #2
        int cb = NQ - 1 - j, tb = NQ - 1 - ((j + 1) % NQ);
        grow[tb] ^= grow[cb]; hcol[cb] ^= hcol[tb];
    }
    for (int q = 0; q < NQ; ++q) P.sgn[q] = grow[NQ - 1 - q];
    return P;
}
constexpr QPlan QP = make_plan();

// Ring-cut decomposition (arcs A={p0..p5}, B={p6..p11}); pinned at compile time.
static_assert(QP.rx2[6] == 0x030 && QP.rx2[7] == 0x018 && QP.rx2[8] == 0x00C &&
              QP.rx2[9] == 0x006 && QP.rx2[10] == 0x003, "A-intra gates");
static_assert(QP.rx2[0] == 0xC00 && QP.rx2[1] == 0x600 && QP.rx2[2] == 0x300 &&
              QP.rx2[3] == 0x180 && QP.rx2[4] == 0x0C0, "B-intra gates");
static_assert(QP.rx2[5] == 0x060 && QP.rx2[11] == 0xC01, "cut gates");

// Expectation plan + Hermitian-parity bookkeeping:
//   T(δ,g) is real when parity(g&δ)=0, imaginary when 1 (T̄ = (−1)^{g·δ} T).
//   be1 = parity(gA&0x20)^parity(gB&0x01)  — gates the sh5 cross term
//   be2 = parity(gA&0x01)^parity(gB&0x30)  — gates the sh11 cross term
//   s3  = parity(gA&0x21)                  — sign of the double-cut term
struct EPlan { unsigned gA[NQ]; unsigned gB[NQ]; unsigned b1mask, b2mask, s3mask; };
constexpr unsigned par(unsigned v) { return __builtin_popcount(v) & 1u; }
constexpr EPlan make_eplan() {
    EPlan E{}; E.b1mask = 0; E.b2mask = 0; E.s3mask = 0;
    for (int q = 0; q < NQ; ++q) {
        unsigned M = QP.sgn[q];
        E.gA[q] = M & 63u;
        E.gB[q] = (M >> 6) & 63u;
        E.b1mask |= (par(E.gA[q] & 0x20u) ^ par(E.gB[q] & 0x01u)) << q;
        E.b2mask |= (par(E.gA[q] & 0x01u) ^ par(E.gB[q] & 0x30u)) << q;
        E.s3mask |= par(E.gA[q] & 0x21u) << q;
    }
    return E;
}
constexpr EPlan EP = make_eplan();

// ---------------------------------------------------------------------------
// One WAVE per batch element; lane l holds arc amplitudes A(l), B(l).
// No LDS, no barriers. All cross-lane traffic is 64-lane shuffles.
// ---------------------------------------------------------------------------
__global__ __launch_bounds__(256) void qsim_fast(
    const float* __restrict__ x, const float* __restrict__ w,
    float* __restrict__ out, int B)
{
    const int wv   = threadIdx.x >> 6;
    const int lane = threadIdx.x & 63;
    const int b    = blockIdx.x * 4 + wv;
    if (b >= B) return;

    // ---- angles: enc+layer0 fused (RX(x)RX(w0)=RX(x+w0)); layer1 separate ----
    float c0[NQ], s0[NQ], c1[NQ], s1[NQ];
    #pragma unroll
    for (int j = 0; j < NQ; ++j) {
        __sincosf(0.5f * (x[b * NQ + j] + w[j]), &s0[j], &c0[j]);
        __sincosf(0.5f * w[NQ + j],              &s1[j], &c1[j]);
    }

    // ---- product-state factors: A over qubits {11..6}, B over {5..0} ----
    float FA = 1.f, FB = 1.f;
    #pragma unroll
    for (int i = 0; i < 6; ++i) {
        FA *= ((lane >> i) & 1) ? s0[11 - i] : c0[11 - i];
        FB *= ((lane >> i) & 1) ? s0[5 - i]  : c0[5 - i];
    }
    const int r = __popc((unsigned)lane) & 3;   // (-i)^r: 1,-i,-1,i
    float aR = (r == 0) ? FA : (r == 2 ? -FA : 0.f);
    float aI = (r == 1) ? -FA : (r == 3 ? FA : 0.f);
    float bR = (r == 0) ? FB : (r == 2 ? -FB : 0.f);
    float bI = (r == 1) ? -FB : (r == 3 ? FB : 0.f);

    // ---- intra-arc gates: z' = c*z - i*s*z(l^m) ----
    auto sgate = [&](float& zr, float& zi, int m, float c, float s) {
        float pr = __shfl_xor(zr, m, 64);
        float pi = __shfl_xor(zi, m, 64);
        zr = fmaf(c, zr,  s * pi);
        zi = fmaf(c, zi, -s * pr);
    };
    sgate(aR, aI, 0x30, c1[6],  s1[6]);
    sgate(aR, aI, 0x18, c1[7],  s1[7]);
    sgate(aR, aI, 0x0C, c1[8],  s1[8]);
    sgate(aR, aI, 0x06, c1[9],  s1[9]);
    sgate(aR, aI, 0x03, c1[10], s1[10]);
    sgate(bR, bI, 0x30, c1[0],  s1[0]);
    sgate(bR, bI, 0x18, c1[1],  s1[1]);
    sgate(bR, bI, 0x0C, c1[2],  s1[2]);
    sgate(bR, bI, 0x06, c1[3],  s1[3]);
    sgate(bR, bI, 0x03, c1[4],  s1[4]);

    // ---- combined correlator input h(u) = Re + Im of V(u^δ)·conj(V(u)).
    // The WHT spectra of Re and Im parts have DISJOINT g-support (Hermitian
    // symmetry), so ONE real WHT of h recovers the needed component at each g:
    //   U(δ,g) = Re T(δ,g) if parity(g&δ)=0, else Im T(δ,g).
    auto corrU = [&](float zr, float zi, int delta) -> float {
        float pr = __shfl_xor(zr, delta, 64);
        float pi = __shfl_xor(zi, delta, 64);
        return (pr * zr + pi * zi) + (pi * zr - pr * zi);
    };
    auto whtr = [&](float& hr) {
        #pragma unroll
        for (int m = 1; m < 64; m <<= 1) {
            float vr = __shfl_xor(hr, m, 64);
            hr = (lane & m) ? vr - hr : hr + vr;
        }
    };

    float UA0  = aR * aR + aI * aI;      whtr(UA0);
    float UA1  = corrU(aR, aI, 0x01);    whtr(UA1);
    float UA20 = corrU(aR, aI, 0x20);    whtr(UA20);
    float UA21 = corrU(aR, aI, 0x21);    whtr(UA21);
    float UB0  = bR * bR + bI * bI;      whtr(UB0);
    float UB01 = corrU(bR, bI, 0x01);    whtr(UB01);
    float UB30 = corrU(bR, bI, 0x30);    whtr(UB30);
    float UB31 = corrU(bR, bI, 0x31);    whtr(UB31);

    // ---- assembly: lane q (<12) computes <Z_q> ----
    int gAi = 0, gBi = 0;
    #pragma unroll
    for (int qq = 0; qq < NQ; ++qq) {
        if (lane == qq) { gAi = (int)EP.gA[qq]; gBi = (int)EP.gB[qq]; }
    }
    const bool be1 = ((unsigned long long)EP.b1mask >> lane) & 1ull;
    const bool be2 = ((unsigned long long)EP.b2mask >> lane) & 1ull;
    const bool s3o = ((unsigned long long)EP.s3mask >> lane) & 1ull;

    float ta0 = __shfl(UA0,  gAi, 64);
    float ta1 = __shfl(UA1,  gAi, 64);
    float ta2 = __shfl(UA20, gAi, 64);
    float ta3 = __shfl(UA21, gAi, 64);
    float tb0 = __shfl(UB0,  gBi, 64);
    float tb1 = __shfl(UB30, gBi, 64);
    float tb2 = __shfl(UB01, gBi, 64);
    float tb3 = __shfl(UB31, gBi, 64);

    // entanglement coefficients: cos/sin of the FULL cut angles
    const float ch5  = c1[5]  * c1[5]  - s1[5]  * s1[5];
    const float sh5  = 2.f * c1[5]  * s1[5];
    const float ch11 = c1[11] * c1[11] - s1[11] * s1[11];
    const float sh11 = 2.f * c1[11] * s1[11];

    const float CA = be1 ? ch5  : 1.f;
    const float CB = be2 ? ch11 : 1.f;
    float res = CA * CB * ta0 * tb0;
    // be2: exactly one of {TA1, TB30} is imaginary -> Im(TA1*TB30) = UA1*UB30
    if (be2) res += CA * sh11 * (ta1 * tb1);
    // be1: exactly one of {TA20, TB01} is imaginary -> Im = UA20*UB01
    if (be1) res += CB * sh5 * (ta2 * tb2);
    // be1&be2: both factors same parity; Re(TA21*TB31) = ±UA21*UB31
    //   res -= sh5*sh11*Re(..) -> sign flips when parity(gA&0x21) is odd
    if (be1 && be2) res += (s3o ? sh5 * sh11 : -sh5 * sh11) * (ta3 * tb3);

    if (lane < NQ) out[b * NQ + lane] = res;
}

// ---------------------------------------------------------------------------
// Generic fallback (any L) — the verified round-2 LDS kernel.
// ---------------------------------------------------------------------------
__global__ __launch_bounds__(256) void qsim_generic(
    const float* __restrict__ x, const float* __restrict__ w,
    float* __restrict__ out, int L)
{
    __shared__ float re[NSTATES];
    __shared__ float im[NSTATES];
    __shared__ float wsum[4][NQ];
    const int b = blockIdx.x;
    const int t = threadIdx.x;

    for (int i = t; i < NSTATES; i += 256) { re[i] = 0.0f; im[i] = 0.0f; }
    if (t == 0) re[0] = 1.0f;
    __syncthreads();

    auto apply_rx = [&](int q, float theta) {
        const int bit = NQ - 1 - q, mask = 1 << bit;
        const float c = cosf(0.5f * theta), s = sinf(0.5f * theta);
        #pragma unroll
        for (int it = 0; it < NSTATES / 2 / 256; ++it) {
            const int p  = t + it * 256;
            const int i0 = ((p >> bit) << (bit + 1)) | (p & (mask - 1));
            const int i1 = i0 | mask;
            const float a0r = re[i0], a0i = im[i0], a1r = re[i1], a1i = im[i1];
            re[i0] = c * a0r + s * a1i;  im[i0] = c * a0i - s * a1r;
            re[i1] = c * a1r + s * a0i;  im[i1] = c * a1i - s * a0r;
        }
        __syncthreads();
    };
    auto apply_cnot = [&](int ctrl, int tgt) {
        const int cbit = NQ - 1 - ctrl, tbit = NQ - 1 - tgt;
        const int lo = cbit < tbit ? cbit : tbit, hi = cbit < tbit ? tbit : cbit;
        #pragma unroll
        for (int it = 0; it < NSTATES / 4 / 256; ++it) {
            const int p  = t + it * 256;
            const int x1 = ((p  >> lo) << (lo + 1)) | (p  & ((1 << lo) - 1));
            const int x2 = ((x1 >> hi) << (hi + 1)) | (x1 & ((1 << hi) - 1));
            const int ia = x2 | (1 << cbit), ib = ia | (1 << tbit);
            const float tr = re[ia]; re[ia] = re[ib]; re[ib] = tr;
            const float ti = im[ia]; im[ia] = im[ib]; im[ib] = ti;
        }
        __syncthreads();
    };

    for (int j = 0; j < NQ; ++j) apply_rx(j, x[b * NQ + j]);
    for (int l2 = 0; l2 < L; ++l2) {
        for (int j = 0; j < NQ; ++j) apply_rx(j, w[l2 * NQ + j]);
        for (int j = 0; j < NQ; ++j) apply_cnot(j, (j + 1) % NQ);
    }

    float ex[NQ];
    #pragma unroll
    for (int q = 0; q < NQ; ++q) ex[q] = 0.0f;
    #pragma unroll
    for (int it = 0; it < NSTATES / 256; ++it) {
        const int i = t + it * 256;
        const float p = re[i] * re[i] + im[i] * im[i];
        #pragma unroll
        for (int q = 0; q < NQ; ++q) ex[q] += ((i >> (NQ - 1 - q)) & 1) ? -p : p;
    }
    #pragma unroll
    for (int q = 0; q < NQ; ++q) {
        float v = ex[q];
        #pragma unroll
        for (int off = 32; off > 0; off >>= 1) v += __shfl_down(v, off, 64);
        ex[q] = v;
    }
    const int wid = t >> 6, lane = t & 63;
    if (lane == 0) {
        #pragma unroll
        for (int q = 0; q < NQ; ++q) wsum[wid][q] = ex[q];
    }
    __syncthreads();
    if (t < NQ) {
        float v = 0.0f;
        #pragma unroll
        for (int k = 0; k < 4; ++k) v += wsum[k][t];
        out[b * NQ + t] = v;
    }
}

extern "C" void kernel_launch(void* const* d_in, const int* in_sizes, int n_in,
                              void* d_out, int out_size, void* d_ws, size_t ws_size,
                              hipStream_t stream) {
    const float* x = (const float*)d_in[0];
    const float* w = (const float*)d_in[1];
    float* out = (float*)d_out;
    const int B = in_sizes[0] / NQ;
    const int L = in_sizes[1] / NQ;
    if (L == 2) {
        qsim_fast<<<dim3((B + 3) / 4), dim3(256), 0, stream>>>(x, w, out, B);
    } else {
        qsim_generic<<<dim3(B), dim3(256), 0, stream>>>(x, w, out, L);
    }
}